// Round 1
// baseline (88.708 us; speedup 1.0000x reference)
//
#include <hip/hip_runtime.h>

// x is (B=2, C=128, H=96, W=96) fp32.
#define BN   2
#define CN   128
#define HN   96
#define WN   96
#define HW   (HN * WN)          // 9216
#define NPIX (BN * HW)          // 18432
#define NP4  (NPIX / 4)         // 4608
#define NMAP 13                 // map 0 = norm^2, maps 1..12 = positive-offset dots
#define EPSV 1e-8f

// Positive half-plane offsets (dy,dx), maps 1..12. dot(p, p+d) == dot(p+d, p).
constexpr int ODY[12] = {0, 0, 1, 1, 1, 1, 1, 2, 2, 2, 2, 2};
constexpr int ODX[12] = {1, 2, -2, -1, 0, 1, 2, -2, -1, 0, 1, 2};

// Kernel 1: full dot/norm maps D[13][NPIX] in one pass.
// Block = (8 px4-lanes x 32 channel-slices), 4 channels per slice.
// Grid = 576 blocks = 2304 waves = 9 waves/CU.
// Reduction: lane = tx + 8*ty (block dim x fastest), so 8 ty-slices live in
// each wave -> 3 butterfly stages via __shfl_xor(8/16/32) in-register, then a
// single LDS round-trip for the 4 per-wave partials (1 barrier vs 10 before,
// 6.9 KB LDS vs 34 KB). LDS strides chosen conflict-free:
//   dword addr = 432*w + 52*tx + 4*m; 52*tx mod 32 covers 8 distinct banks.
__global__ void __launch_bounds__(256) k_maps(const float* __restrict__ x,
                                              float* __restrict__ D) {
    const int tx = threadIdx.x;                        // 0..7  (px4 lane)
    const int ty = threadIdx.y;                        // 0..31 (channel slice)
    int p4 = blockIdx.x * 8 + tx;                      // 0..NP4-1
    int pix = p4 * 4;
    int b = pix / HW;
    int hw = pix - b * HW;
    int h = hw / WN;
    int w = hw - h * WN;                               // multiple of 4
    const float* xb = x + ((size_t)b * CN + (size_t)ty * 4) * HW + h * WN + w;

    float acc[NMAP][4];
#pragma unroll
    for (int m = 0; m < NMAP; ++m)
#pragma unroll
        for (int i = 0; i < 4; ++i) acc[m][i] = 0.f;

#pragma unroll
    for (int cc = 0; cc < 4; ++cc) {
        const float* cp = xb + (size_t)cc * HW;
        float r[3][8];                                 // cols w-2 .. w+5
        {   // row 0 (always in-bounds): only cols w..w+5 needed
            float4 a1 = *(const float4*)cp;            // cols w..w+3
            float2 hi = make_float2(0.f, 0.f);
            if (w + 4 < WN) hi = *(const float2*)(cp + 4);   // cols w+4,w+5
            r[0][0] = 0.f;  r[0][1] = 0.f;
            r[0][2] = a1.x; r[0][3] = a1.y; r[0][4] = a1.z; r[0][5] = a1.w;
            r[0][6] = hi.x; r[0][7] = hi.y;
        }
#pragma unroll
        for (int ry = 1; ry < 3; ++ry) {
            float2 lo = make_float2(0.f, 0.f);
            float4 a1 = make_float4(0.f, 0.f, 0.f, 0.f);
            float2 hi = make_float2(0.f, 0.f);
            if (h + ry < HN) {
                const float* rp = cp + ry * WN;
                if (w > 0)      lo = *(const float2*)(rp - 2);   // cols w-2,w-1
                a1 = *(const float4*)rp;                          // cols w..w+3
                if (w + 4 < WN) hi = *(const float2*)(rp + 4);   // cols w+4,w+5
            }
            r[ry][0] = lo.x; r[ry][1] = lo.y;
            r[ry][2] = a1.x; r[ry][3] = a1.y; r[ry][4] = a1.z; r[ry][5] = a1.w;
            r[ry][6] = hi.x; r[ry][7] = hi.y;
        }
#pragma unroll
        for (int i = 0; i < 4; ++i) {
            float c = r[0][2 + i];
            acc[0][i] += c * c;
#pragma unroll
            for (int j = 0; j < 12; ++j)
                acc[j + 1][i] += c * r[ODY[j]][2 + i + ODX[j]];
        }
    }

    // Stage 1: butterfly over the 8 ty-slices inside each wave.
    // lane = tx + 8*(ty&7): xor masks 8,16,32 flip the ty bits.
#pragma unroll
    for (int m = 0; m < NMAP; ++m)
#pragma unroll
        for (int i = 0; i < 4; ++i) {
            float v = acc[m][i];
            v += __shfl_xor(v, 8);
            v += __shfl_xor(v, 16);
            v += __shfl_xor(v, 32);
            acc[m][i] = v;
        }

    // Stage 2: one LDS round-trip for the 4 per-wave partials.
    constexpr int RS = 108;                            // float4 stride per wave
    __shared__ float4 red[4 * RS];                     // 6912 B
    if ((ty & 7) == 0) {
        int wv = ty >> 3;
#pragma unroll
        for (int m = 0; m < NMAP; ++m)
            red[wv * RS + tx * NMAP + m] =
                make_float4(acc[m][0], acc[m][1], acc[m][2], acc[m][3]);
    }
    __syncthreads();
    if (ty == 0) {
#pragma unroll
        for (int m = 0; m < NMAP; ++m) {
            float4 a = red[0 * RS + tx * NMAP + m];
            float4 b4 = red[1 * RS + tx * NMAP + m];
            float4 c4 = red[2 * RS + tx * NMAP + m];
            float4 d4 = red[3 * RS + tx * NMAP + m];
            *(float4*)(D + (size_t)m * NPIX + pix) = make_float4(
                a.x + b4.x + c4.x + d4.x,
                a.y + b4.y + c4.y + d4.y,
                a.z + b4.z + c4.z + d4.z,
                a.w + b4.w + c4.w + d4.w);
        }
    }
}

// Kernel 2: fused count + apply, de-duplicated.
// Block = 256 threads over 64 consecutive pixels (one b each: 9216 % 64 == 0).
// Phase 1: threads 0..63 compute the 24-term count ONCE per pixel -> LDS.
// Phase 2: stream 64 channels x 64 pixels as float4 (lane g = t&15 owns pixel
// quad 4g..4g+3, cb = t>>4 walks channels in strides of 16 -> 256 B contiguous
// per 16-lane group, fully coalesced). Count redundancy 8x -> 2x (CSPLIT=2),
// memory instructions 4x fewer.
#define KCSPLIT 2
#define KCG (CN / KCSPLIT)                             // 64
__global__ void __launch_bounds__(256) k_maskapply(const float* __restrict__ x,
                                                   const float* __restrict__ D,
                                                   const float* __restrict__ thr2p,
                                                   float* __restrict__ out) {
    const int t = threadIdx.x;
    const int pbase = blockIdx.x * 64;
    const int cg = blockIdx.y;
    __shared__ __align__(16) float scale[64];

    if (t < 64) {
        int p = pbase + t;
        const float t2 = *thr2p;
        int b = p / HW;
        int hw = p - b * HW;
        int h = hw / WN, w = hw - h * WN;

        float nc = sqrtf(D[p]);                        // map 0 = norm^2
        int count = 0;
#pragma unroll
        for (int j = 0; j < 12; ++j) {
            const int dy = ODY[j], dx = ODX[j];
            const float* Dj = D + (size_t)(j + 1) * NPIX;
            // positive direction: neighbor (h+dy, w+dx); dot stored at p
            {
                float sim = 0.f;
                if (h + dy < HN && w + dx >= 0 && w + dx < WN) {
                    int q = p + dy * WN + dx;
                    sim = Dj[p] / fmaxf(nc * sqrtf(D[q]), EPSV);
                }
                count += (sim < t2) ? 1 : 0;
            }
            // negative direction: neighbor q = p - d; dot stored at q
            {
                float sim = 0.f;
                if (h - dy >= 0 && w - dx >= 0 && w - dx < WN) {
                    int q = p - (dy * WN + dx);
                    sim = Dj[q] / fmaxf(nc * sqrtf(D[q]), EPSV);
                }
                count += (sim < t2) ? 1 : 0;
            }
        }
        scale[t] = 1.f + sqrtf((float)count);
    }
    __syncthreads();

    const int g  = t & 15;                             // pixel quad within block
    const int cb = t >> 4;                             // channel offset 0..15
    int b = pbase / HW;
    int hwb = pbase - b * HW + 4 * g;
    float4 s4 = *(const float4*)&scale[4 * g];
    const size_t base0 = ((size_t)b * CN + (size_t)cg * KCG + cb) * HW + hwb;
#pragma unroll
    for (int k = 0; k < KCG / 16; ++k) {               // 4 iterations
        size_t off = base0 + (size_t)k * 16 * HW;
        float4 v = *(const float4*)(x + off);
        v.x *= s4.x; v.y *= s4.y; v.z *= s4.z; v.w *= s4.w;
        *(float4*)(out + off) = v;
    }
}

extern "C" void kernel_launch(void* const* d_in, const int* in_sizes, int n_in,
                              void* d_out, int out_size, void* d_ws, size_t ws_size,
                              hipStream_t stream) {
    const float* x    = (const float*)d_in[0];
    // d_in[1] = edge_threshold1: unused — cosine sim is invariant under the
    // per-pixel positive rescale x_mask = x*(1+m1), so the 9x9 pass is dead.
    const float* thr2 = (const float*)d_in[2];
    float* out = (float*)d_out;

    float* D = (float*)d_ws;                           // NMAP*NPIX floats (~958 KB)

    k_maps<<<dim3(NP4 / 8), dim3(8, 32), 0, stream>>>(x, D);
    k_maskapply<<<dim3(NPIX / 64, KCSPLIT), 256, 0, stream>>>(x, D, thr2, out);
}